// Round 9
// baseline (229.672 us; speedup 1.0000x reference)
//
#include <hip/hip_runtime.h>
#include <hip/hip_bf16.h>

// Established: inputs f32, output f32. Threshold 0.038; r3-r7 absmax 0.0078 (1 bf16 ulp).
// Math: y = (rec + DELTA*(cat(du,u)@Bw^T)) @ Cw^T,  rec = h + 0.005*(W@h - W^T@h)
// (expm/inv series truncated at X^1; X^2+ terms <4e-5 -> dropped, validated r3-r7).
// Harness floor ~57us GPU-busy (268MB ws poison + restores).
// r8 cooperative launch FAILED (grid 1024 > co-residency) -> r9: DIY strip-level
// producer-consumer in one 512-block kernel; co-residency forced by launch_bounds(256,2).

#define B_SZ 512
#define U_DIM 1024
#define DU_DIM 512
#define H_DIM 2048
#define Y_DIM 1024
#define K_CAT 1536
#define DELTA_F 0.01f

typedef __hip_bfloat16 bf16;
using bf16x8f = __attribute__((ext_vector_type(8))) short;
using f32x4   = __attribute__((ext_vector_type(4))) float;

__device__ __forceinline__ short f2bs(float x) {
  union { bf16 b; short s; } u; u.b = __float2bfloat16(x); return u.s;
}
__device__ __forceinline__ int4 pack8(const float4 v0, const float4 v1) {
  union { short s[8]; int4 i; } o;
  o.s[0] = f2bs(v0.x); o.s[1] = f2bs(v0.y); o.s[2] = f2bs(v0.z); o.s[3] = f2bs(v0.w);
  o.s[4] = f2bs(v1.x); o.s[5] = f2bs(v1.y); o.s[6] = f2bs(v1.z); o.s[7] = f2bs(v1.w);
  return o.i;
}

#define LDP 72  // padded LDS row stride in shorts (144B -> 2-way banking, free per m136)
#define LDS_SHORTS (2 * 32 * LDP + 2 * 64 * LDP)

// ---- K2 tile: bb[32x64] = bf16(rec[col] + DELTA*(z[32xK] @ Bwb[64xK]^T)) [r7-verified] ----
__device__ __forceinline__ void k2_tile(short* lds, float* recf, const short* __restrict__ A,
                                        const short* __restrict__ B, const float* __restrict__ h,
                                        const float* __restrict__ wh, const float* __restrict__ wtp,
                                        short* __restrict__ out, int mt, int nt) {
  const int KDIM = K_CAT;
  short* As0 = lds;
  short* Bs0 = lds + 2 * 32 * LDP;
  const int tid = threadIdx.x;
  const int lane = tid & 63, wave = tid >> 6;
  const int wm = wave >> 1, wn = wave & 1;
  const int row0 = mt * 32, col0 = nt * 64;
  const int rA = tid >> 3, kc = (tid & 7) * 8;
  f32x4 acc[2] = {};
  int4 pa, pb1, pb2;
  auto ldA  = [&](int kt) { return *(const int4*)(A + (size_t)(row0 + rA) * KDIM + kt * 64 + kc); };
  auto ldB1 = [&](int kt) { return *(const int4*)(B + (size_t)(col0 + rA) * KDIM + kt * 64 + kc); };
  auto ldB2 = [&](int kt) { return *(const int4*)(B + (size_t)(col0 + rA + 32) * KDIM + kt * 64 + kc); };
  pa = ldA(0); pb1 = ldB1(0); pb2 = ldB2(0);
  *(int4*)&As0[rA * LDP + kc] = pa;
  *(int4*)&Bs0[rA * LDP + kc] = pb1;
  *(int4*)&Bs0[(rA + 32) * LDP + kc] = pb2;
  const int NT = KDIM / 64;
  const int kq = (lane >> 4) * 8, rm = lane & 15;
  for (int kt = 0; kt < NT; kt++) {
    const int cur = kt & 1;
    if (kt + 1 < NT) { pa = ldA(kt + 1); pb1 = ldB1(kt + 1); pb2 = ldB2(kt + 1); }
    __syncthreads();
    const short* Ac = As0 + cur * (32 * LDP);
    const short* Bc = Bs0 + cur * (64 * LDP);
    bf16x8f af[2], bfr[2][2];
#pragma unroll
    for (int ks = 0; ks < 2; ks++) {
      af[ks] = *(const bf16x8f*)&Ac[(wm * 16 + rm) * LDP + ks * 32 + kq];
#pragma unroll
      for (int j = 0; j < 2; j++)
        bfr[ks][j] = *(const bf16x8f*)&Bc[(wn * 32 + 16 * j + rm) * LDP + ks * 32 + kq];
    }
#pragma unroll
    for (int ks = 0; ks < 2; ks++)
#pragma unroll
      for (int j = 0; j < 2; j++)
        acc[j] = __builtin_amdgcn_mfma_f32_16x16x32_bf16(af[ks], bfr[ks][j], acc[j], 0, 0, 0);
    if (kt + 1 < NT) {
      short* An = As0 + (cur ^ 1) * (32 * LDP);
      short* Bn = Bs0 + (cur ^ 1) * (64 * LDP);
      *(int4*)&An[rA * LDP + kc] = pa;
      *(int4*)&Bn[rA * LDP + kc] = pb1;
      *(int4*)&Bn[(rA + 32) * LDP + kc] = pb2;
      __syncthreads();
    }
  }
  // rec[c] = h[c] + 0.005*(wh[c] - sum_p wtp[p][c])
  if (tid < 64) {
    int gc = col0 + tid;
    float s = 0.f;
#pragma unroll
    for (int p = 0; p < 32; p++) s += wtp[p * H_DIM + gc];
    recf[tid] = h[gc] + 0.005f * (wh[gc] - s);
  }
  __syncthreads();
  const int quad = lane >> 4;
#pragma unroll
  for (int j = 0; j < 2; j++) {
    int gc = col0 + wn * 32 + 16 * j + rm;
#pragma unroll
    for (int r = 0; r < 4; r++) {
      int gr = row0 + wm * 16 + quad * 4 + r;
      out[(size_t)gr * H_DIM + gc] = f2bs(recf[gc - col0] + DELTA_F * acc[j][r]);
    }
  }
}

// ---- K3 tile: y[32x32] = bb[32xK] @ Cwb[32xK]^T (f32 out), waves 2x2 of 16x16 ----
__device__ __forceinline__ void k3_tile(short* lds, const short* __restrict__ A,
                                        const short* __restrict__ B, float* __restrict__ out,
                                        int mt, int nt) {
  const int KDIM = H_DIM;
  short* As0 = lds;                  // [2][32*LDP]
  short* Bs0 = lds + 2 * 32 * LDP;   // [2][32*LDP]
  const int tid = threadIdx.x;
  const int lane = tid & 63, wave = tid >> 6;
  const int wm = wave >> 1, wn = wave & 1;
  const int row0 = mt * 32, col0 = nt * 32;
  const int rA = tid >> 3, kc = (tid & 7) * 8;
  f32x4 acc = {};
  int4 pa, pb;
  auto ldA = [&](int kt) { return *(const int4*)(A + (size_t)(row0 + rA) * KDIM + kt * 64 + kc); };
  auto ldB = [&](int kt) { return *(const int4*)(B + (size_t)(col0 + rA) * KDIM + kt * 64 + kc); };
  pa = ldA(0); pb = ldB(0);
  *(int4*)&As0[rA * LDP + kc] = pa;
  *(int4*)&Bs0[rA * LDP + kc] = pb;
  const int NT = KDIM / 64;
  const int kq = (lane >> 4) * 8, rm = lane & 15;
  for (int kt = 0; kt < NT; kt++) {
    const int cur = kt & 1;
    if (kt + 1 < NT) { pa = ldA(kt + 1); pb = ldB(kt + 1); }
    __syncthreads();
    const short* Ac = As0 + cur * (32 * LDP);
    const short* Bc = Bs0 + cur * (32 * LDP);
#pragma unroll
    for (int ks = 0; ks < 2; ks++) {
      bf16x8f af = *(const bf16x8f*)&Ac[(wm * 16 + rm) * LDP + ks * 32 + kq];
      bf16x8f bf = *(const bf16x8f*)&Bc[(wn * 16 + rm) * LDP + ks * 32 + kq];
      acc = __builtin_amdgcn_mfma_f32_16x16x32_bf16(af, bf, acc, 0, 0, 0);
    }
    if (kt + 1 < NT) {
      short* An = As0 + (cur ^ 1) * (32 * LDP);
      short* Bn = Bs0 + (cur ^ 1) * (32 * LDP);
      *(int4*)&An[rA * LDP + kc] = pa;
      *(int4*)&Bn[rA * LDP + kc] = pb;
      __syncthreads();
    }
  }
  const int quad = lane >> 4;
  int gc = col0 + wn * 16 + rm;
#pragma unroll
  for (int r = 0; r < 4; r++) {
    int gr = row0 + wm * 16 + quad * 4 + r;
    out[(size_t)gr * Y_DIM + gc] = acc[r];
  }
}

// ---------------- K1 [r7-verified]: wh (0..511), wtp partials (512..767), ----------------
// ----------------                   cvt z|Bw|Cw -> bf16 (768..1279)        ----------------
#define NZ (B_SZ * K_CAT / 8)
#define NB (H_DIM * K_CAT / 8)
#define NC (Y_DIM * H_DIM / 8)

__global__ __launch_bounds__(256) void k1(const float* __restrict__ W, const float* __restrict__ h,
                                          const float* __restrict__ du, const float* __restrict__ u,
                                          const float* __restrict__ Bw, const float* __restrict__ Cw,
                                          float* __restrict__ wh, float* __restrict__ wtp,
                                          short* __restrict__ z, short* __restrict__ Bwb,
                                          short* __restrict__ Cwb) {
  const int b = blockIdx.x;
  if (b < 512) {
    const int lane = threadIdx.x & 63, wave = threadIdx.x >> 6;
    const int row = b * 4 + wave;
    const float* wr = W + (size_t)row * H_DIM;
    float s = 0.f;
#pragma unroll
    for (int it = 0; it < 8; it++) {
      int k = it * 256 + lane * 4;
      float4 a = *(const float4*)(wr + k);
      float4 hv = *(const float4*)(h + k);
      s += a.x * hv.x + a.y * hv.y + a.z * hv.z + a.w * hv.w;
    }
#pragma unroll
    for (int off = 32; off > 0; off >>= 1) s += __shfl_down(s, off);
    if (lane == 0) wh[row] = s;
  } else if (b < 768) {
    const int e = b - 512;
    const int colg = e & 7, rowg = e >> 3;
    const int k = colg * 256 + threadIdx.x;
    float s = 0.f;
    const float* base = W + (size_t)rowg * 64 * H_DIM + k;
#pragma unroll 8
    for (int i = 0; i < 64; i++) s += base[(size_t)i * H_DIM] * h[rowg * 64 + i];
    wtp[rowg * H_DIM + k] = s;
  } else {
    const int NG = NZ + NB + NC;
    for (int g = (b - 768) * 256 + threadIdx.x; g < NG; g += 512 * 256) {
      const float* src; short* dst;
      if (g < NZ) {
        int e = g * 8, row = e / K_CAT, col = e % K_CAT;
        src = (col < DU_DIM) ? du + (size_t)row * DU_DIM + col
                             : u + (size_t)row * U_DIM + (col - DU_DIM);
        dst = z + e;
      } else if (g < NZ + NB) {
        int e = (g - NZ) * 8; src = Bw + e; dst = Bwb + e;
      } else {
        int e = (g - NZ - NB) * 8; src = Cw + e; dst = Cwb + e;
      }
      *(int4*)dst = pack8(*(const float4*)src, *(const float4*)(src + 4));
    }
  }
}

// ---------------- K23: fused k2 + strip-flag + k3. 512 blocks, 2 blocks/CU forced ----------
// Deadlock-free: launch_bounds(256,2) caps VGPR<=256 -> >=2 blocks/CU; LDS 2x28KB<=160KB;
// 8 waves <= 32  => all 512 blocks co-resident. Strip mt complete when flags[mt]==32.
__global__ __launch_bounds__(256, 2) void k23(const short* __restrict__ z, const short* __restrict__ Bwb,
                                              const float* __restrict__ h, const float* __restrict__ wh,
                                              const float* __restrict__ wtp, short* __restrict__ bb,
                                              const short* __restrict__ Cwb, float* __restrict__ y,
                                              int* __restrict__ flags) {
  __shared__ __align__(16) short lds[LDS_SHORTS];
  __shared__ float recf[64];
  const int b = blockIdx.x;
  const int mt = b >> 5, nt = b & 31;

  // phase A: bb strip mt, cols nt*64..+63
  k2_tile(lds, recf, z, Bwb, h, wh, wtp, bb, mt, nt);

  // release: my stores -> visible, then count this tile
  __threadfence();
  __syncthreads();
  if (threadIdx.x == 0) {
    __hip_atomic_fetch_add(&flags[mt], 1, __ATOMIC_RELEASE, __HIP_MEMORY_SCOPE_AGENT);
    // acquire-spin until all 32 tiles of my strip are done
    while (__hip_atomic_load(&flags[mt], __ATOMIC_ACQUIRE, __HIP_MEMORY_SCOPE_AGENT) < 32)
      __builtin_amdgcn_s_sleep(2);
  }
  __syncthreads();
  __threadfence();  // acquire side: invalidate stale cache lines for bb

  // phase B: y tile (mt, nt) of 16 x 32 grid (32x32 tile)
  k3_tile(lds, bb, Cwb, y, mt, nt);
}

extern "C" void kernel_launch(void* const* d_in, const int* in_sizes, int n_in,
                              void* d_out, int out_size, void* d_ws, size_t ws_size,
                              hipStream_t stream) {
  const float* u  = (const float*)d_in[0];
  const float* du = (const float*)d_in[1];
  const float* W  = (const float*)d_in[2];
  const float* Bw = (const float*)d_in[3];
  const float* Cw = (const float*)d_in[4];
  const float* h  = (const float*)d_in[5];
  float* y = (float*)d_out;

  char* w = (char*)d_ws;
  size_t off = 0;
  short* z   = (short*)(w + off); off += (size_t)B_SZ * K_CAT * sizeof(short);
  short* Bwb = (short*)(w + off); off += (size_t)H_DIM * K_CAT * sizeof(short);
  short* Cwb = (short*)(w + off); off += (size_t)Y_DIM * H_DIM * sizeof(short);
  short* bb  = (short*)(w + off); off += (size_t)B_SZ * H_DIM * sizeof(short);
  float* wh  = (float*)(w + off); off += H_DIM * sizeof(float);
  float* wtp = (float*)(w + off); off += 32 * H_DIM * sizeof(float);
  int* flags = (int*)(w + off);   off += 16 * sizeof(int);
  if (ws_size < off) return;

  hipMemsetAsync(flags, 0, 16 * sizeof(int), stream);  // ws is poisoned 0xAA
  k1<<<1280, 256, 0, stream>>>(W, h, du, u, Bw, Cw, wh, wtp, z, Bwb, Cwb);
  k23<<<512, 256, 0, stream>>>(z, Bwb, h, wh, wtp, bb, Cwb, y, flags);
}

// Round 10
// 121.781 us; speedup vs baseline: 1.8859x; 1.8859x over previous
//
#include <hip/hip_runtime.h>
#include <hip/hip_bf16.h>

// Established: inputs f32, output f32. Threshold 0.038; absmax floor 0.0078 (1 bf16 ulp).
// Math: y = (rec + DELTA*(cat(du,u)@Bw^T)) @ Cw^T,  rec = h + 0.005*(W@h - W^T@h)
// (expm/inv series truncated at X^1; X^2+ terms <4e-5, validated r3-r9).
// r9 lesson: intra-kernel barrier/spin fusion catastrophically slow (spill + stall);
// 3-kernel r7 skeleton is the base. r10: z inlined into k2 staging, Cw cvt overlapped
// with k2 GEMM, k3 at 512 blocks (32x32 tiles, r9-correctness-verified).

#define B_SZ 512
#define U_DIM 1024
#define DU_DIM 512
#define H_DIM 2048
#define Y_DIM 1024
#define K_CAT 1536
#define DELTA_F 0.01f

typedef __hip_bfloat16 bf16;
using bf16x8f = __attribute__((ext_vector_type(8))) short;
using f32x4   = __attribute__((ext_vector_type(4))) float;

__device__ __forceinline__ short f2bs(float x) {
  union { bf16 b; short s; } u; u.b = __float2bfloat16(x); return u.s;
}
__device__ __forceinline__ int4 pack8(const float4 v0, const float4 v1) {
  union { short s[8]; int4 i; } o;
  o.s[0] = f2bs(v0.x); o.s[1] = f2bs(v0.y); o.s[2] = f2bs(v0.z); o.s[3] = f2bs(v0.w);
  o.s[4] = f2bs(v1.x); o.s[5] = f2bs(v1.y); o.s[6] = f2bs(v1.z); o.s[7] = f2bs(v1.w);
  return o.i;
}

#define LDP 72  // padded LDS row stride in shorts (144B -> 2-way banking, free per m136)
#define LDS_SHORTS (2 * 32 * LDP + 2 * 64 * LDP)

// ---------------- K1: wh (0..511), wtp partials (512..767), Bw cvt (768..1023) ----------------
#define NB (H_DIM * K_CAT / 8)

__global__ __launch_bounds__(256) void k1(const float* __restrict__ W, const float* __restrict__ h,
                                          const float* __restrict__ Bw, float* __restrict__ wh,
                                          float* __restrict__ wtp, short* __restrict__ Bwb) {
  const int b = blockIdx.x;
  if (b < 512) {  // wh[row] = dot(W[row,:], h)
    const int lane = threadIdx.x & 63, wave = threadIdx.x >> 6;
    const int row = b * 4 + wave;
    const float* wr = W + (size_t)row * H_DIM;
    float s = 0.f;
#pragma unroll
    for (int it = 0; it < 8; it++) {
      int k = it * 256 + lane * 4;
      float4 a = *(const float4*)(wr + k);
      float4 hv = *(const float4*)(h + k);
      s += a.x * hv.x + a.y * hv.y + a.z * hv.z + a.w * hv.w;
    }
#pragma unroll
    for (int off = 32; off > 0; off >>= 1) s += __shfl_down(s, off);
    if (lane == 0) wh[row] = s;
  } else if (b < 768) {  // wtp[rowg][k] = sum over 64-row chunk of W[i][k]*h[i]
    const int e = b - 512;
    const int colg = e & 7, rowg = e >> 3;
    const int k = colg * 256 + threadIdx.x;
    float s = 0.f;
    const float* base = W + (size_t)rowg * 64 * H_DIM + k;
#pragma unroll 8
    for (int i = 0; i < 64; i++) s += base[(size_t)i * H_DIM] * h[rowg * 64 + i];
    wtp[rowg * H_DIM + k] = s;
  } else {  // Bw -> bf16
    for (int g = (b - 768) * 256 + threadIdx.x; g < NB; g += 256 * 256) {
      int e = g * 8;
      *(int4*)(Bwb + e) = pack8(*(const float4*)(Bw + e), *(const float4*)(Bw + e + 4));
    }
  }
}

// ---- K2 GEMM tile: bb[32x64] = bf16(rec[col] + DELTA*(cat(du,u)[32xK] @ Bwb[64xK]^T)) ----
__device__ __forceinline__ void k2_tile(short* lds, float* recf, const float* __restrict__ du,
                                        const float* __restrict__ u, const short* __restrict__ B,
                                        const float* __restrict__ h, const float* __restrict__ wh,
                                        const float* __restrict__ wtp, short* __restrict__ out,
                                        int mt, int nt) {
  const int KDIM = K_CAT;
  short* As0 = lds;
  short* Bs0 = lds + 2 * 32 * LDP;
  const int tid = threadIdx.x;
  const int lane = tid & 63, wave = tid >> 6;
  const int wm = wave >> 1, wn = wave & 1;
  const int row0 = mt * 32, col0 = nt * 64;
  const int rA = tid >> 3, kc = (tid & 7) * 8;
  f32x4 acc[2] = {};
  int4 pa, pb1, pb2;
  auto ldA = [&](int kt) -> int4 {  // inline f32->bf16; granule (8 floats) never straddles 512
    int col = kt * 64 + kc;
    const float* p = (col < DU_DIM) ? du + (size_t)(row0 + rA) * DU_DIM + col
                                    : u + (size_t)(row0 + rA) * U_DIM + (col - DU_DIM);
    return pack8(*(const float4*)p, *(const float4*)(p + 4));
  };
  auto ldB1 = [&](int kt) { return *(const int4*)(B + (size_t)(col0 + rA) * KDIM + kt * 64 + kc); };
  auto ldB2 = [&](int kt) { return *(const int4*)(B + (size_t)(col0 + rA + 32) * KDIM + kt * 64 + kc); };
  pa = ldA(0); pb1 = ldB1(0); pb2 = ldB2(0);
  *(int4*)&As0[rA * LDP + kc] = pa;
  *(int4*)&Bs0[rA * LDP + kc] = pb1;
  *(int4*)&Bs0[(rA + 32) * LDP + kc] = pb2;
  const int NT = KDIM / 64;
  const int kq = (lane >> 4) * 8, rm = lane & 15;
  for (int kt = 0; kt < NT; kt++) {
    const int cur = kt & 1;
    if (kt + 1 < NT) { pa = ldA(kt + 1); pb1 = ldB1(kt + 1); pb2 = ldB2(kt + 1); }
    __syncthreads();
    const short* Ac = As0 + cur * (32 * LDP);
    const short* Bc = Bs0 + cur * (64 * LDP);
    bf16x8f af[2], bfr[2][2];
#pragma unroll
    for (int ks = 0; ks < 2; ks++) {
      af[ks] = *(const bf16x8f*)&Ac[(wm * 16 + rm) * LDP + ks * 32 + kq];
#pragma unroll
      for (int j = 0; j < 2; j++)
        bfr[ks][j] = *(const bf16x8f*)&Bc[(wn * 32 + 16 * j + rm) * LDP + ks * 32 + kq];
    }
#pragma unroll
    for (int ks = 0; ks < 2; ks++)
#pragma unroll
      for (int j = 0; j < 2; j++)
        acc[j] = __builtin_amdgcn_mfma_f32_16x16x32_bf16(af[ks], bfr[ks][j], acc[j], 0, 0, 0);
    if (kt + 1 < NT) {
      short* An = As0 + (cur ^ 1) * (32 * LDP);
      short* Bn = Bs0 + (cur ^ 1) * (64 * LDP);
      *(int4*)&An[rA * LDP + kc] = pa;
      *(int4*)&Bn[rA * LDP + kc] = pb1;
      *(int4*)&Bn[(rA + 32) * LDP + kc] = pb2;
      __syncthreads();
    }
  }
  if (tid < 64) {  // rec[c] = h[c] + 0.005*(wh[c] - sum_p wtp[p][c])
    int gc = col0 + tid;
    float s = 0.f;
#pragma unroll
    for (int p = 0; p < 32; p++) s += wtp[p * H_DIM + gc];
    recf[tid] = h[gc] + 0.005f * (wh[gc] - s);
  }
  __syncthreads();
  const int quad = lane >> 4;
#pragma unroll
  for (int j = 0; j < 2; j++) {
    int gc = col0 + wn * 32 + 16 * j + rm;
#pragma unroll
    for (int r = 0; r < 4; r++) {
      int gr = row0 + wm * 16 + quad * 4 + r;
      out[(size_t)gr * H_DIM + gc] = f2bs(recf[gc - col0] + DELTA_F * acc[j][r]);
    }
  }
}

// ---------------- K2: 512 GEMM tiles + 512 Cw-cvt blocks (overlapped) ----------------
__global__ __launch_bounds__(256) void k2(const float* __restrict__ du, const float* __restrict__ u,
                                          const short* __restrict__ Bwb, const float* __restrict__ h,
                                          const float* __restrict__ wh, const float* __restrict__ wtp,
                                          short* __restrict__ bb, const float* __restrict__ Cw,
                                          short* __restrict__ Cwb) {
  __shared__ __align__(16) short lds[LDS_SHORTS];
  __shared__ float recf[64];
  const int b = blockIdx.x;
  if (b < 512) {
    k2_tile(lds, recf, du, u, Bwb, h, wh, wtp, bb, b >> 5, b & 31);
  } else {  // Cw -> bf16 (consumed only by k3; hidden behind GEMM tiles)
    int g = (b - 512) * 256 + threadIdx.x;  // NC granules = 262144 = 512*256*2
    int e = g * 8;
    *(int4*)(Cwb + e) = pack8(*(const float4*)(Cw + e), *(const float4*)(Cw + e + 4));
    e = (g + 131072) * 8;
    *(int4*)(Cwb + e) = pack8(*(const float4*)(Cw + e), *(const float4*)(Cw + e + 4));
  }
}

// ---------------- K3: y[32x32] tiles = bb @ Cwb^T (f32), 512 blocks [r9-verified] ----------------
__global__ __launch_bounds__(256) void k3(const short* __restrict__ A, const short* __restrict__ B,
                                          float* __restrict__ y) {
  __shared__ __align__(16) short lds[LDS_SHORTS];
  const int KDIM = H_DIM;
  short* As0 = lds;
  short* Bs0 = lds + 2 * 32 * LDP;
  const int tid = threadIdx.x;
  const int lane = tid & 63, wave = tid >> 6;
  const int wm = wave >> 1, wn = wave & 1;
  const int mt = blockIdx.x >> 5, nt = blockIdx.x & 31;
  const int row0 = mt * 32, col0 = nt * 32;
  const int rA = tid >> 3, kc = (tid & 7) * 8;
  f32x4 acc = {};
  int4 pa, pb;
  auto ldA = [&](int kt) { return *(const int4*)(A + (size_t)(row0 + rA) * KDIM + kt * 64 + kc); };
  auto ldB = [&](int kt) { return *(const int4*)(B + (size_t)(col0 + rA) * KDIM + kt * 64 + kc); };
  pa = ldA(0); pb = ldB(0);
  *(int4*)&As0[rA * LDP + kc] = pa;
  *(int4*)&Bs0[rA * LDP + kc] = pb;
  const int NT = KDIM / 64;
  const int kq = (lane >> 4) * 8, rm = lane & 15;
  for (int kt = 0; kt < NT; kt++) {
    const int cur = kt & 1;
    if (kt + 1 < NT) { pa = ldA(kt + 1); pb = ldB(kt + 1); }
    __syncthreads();
    const short* Ac = As0 + cur * (32 * LDP);
    const short* Bc = Bs0 + cur * (32 * LDP);
#pragma unroll
    for (int ks = 0; ks < 2; ks++) {
      bf16x8f af = *(const bf16x8f*)&Ac[(wm * 16 + rm) * LDP + ks * 32 + kq];
      bf16x8f bf = *(const bf16x8f*)&Bc[(wn * 16 + rm) * LDP + ks * 32 + kq];
      acc = __builtin_amdgcn_mfma_f32_16x16x32_bf16(af, bf, acc, 0, 0, 0);
    }
    if (kt + 1 < NT) {
      short* An = As0 + (cur ^ 1) * (32 * LDP);
      short* Bn = Bs0 + (cur ^ 1) * (32 * LDP);
      *(int4*)&An[rA * LDP + kc] = pa;
      *(int4*)&Bn[rA * LDP + kc] = pb;
      __syncthreads();
    }
  }
  const int quad = lane >> 4;
  int gc = col0 + wn * 16 + rm;
#pragma unroll
  for (int r = 0; r < 4; r++) {
    int gr = row0 + wm * 16 + quad * 4 + r;
    y[(size_t)gr * Y_DIM + gc] = acc[r];
  }
}

extern "C" void kernel_launch(void* const* d_in, const int* in_sizes, int n_in,
                              void* d_out, int out_size, void* d_ws, size_t ws_size,
                              hipStream_t stream) {
  const float* u  = (const float*)d_in[0];
  const float* du = (const float*)d_in[1];
  const float* W  = (const float*)d_in[2];
  const float* Bw = (const float*)d_in[3];
  const float* Cw = (const float*)d_in[4];
  const float* h  = (const float*)d_in[5];
  float* y = (float*)d_out;

  char* w = (char*)d_ws;
  size_t off = 0;
  short* Bwb = (short*)(w + off); off += (size_t)H_DIM * K_CAT * sizeof(short);  // 6 MB
  short* Cwb = (short*)(w + off); off += (size_t)Y_DIM * H_DIM * sizeof(short);  // 4 MB
  short* bb  = (short*)(w + off); off += (size_t)B_SZ * H_DIM * sizeof(short);   // 2 MB
  float* wh  = (float*)(w + off); off += H_DIM * sizeof(float);
  float* wtp = (float*)(w + off); off += 32 * H_DIM * sizeof(float);
  if (ws_size < off) return;

  k1<<<1024, 256, 0, stream>>>(W, h, Bw, wh, wtp, Bwb);
  k2<<<1024, 256, 0, stream>>>(du, u, Bwb, h, wh, wtp, bb, Cw, Cwb);
  k3<<<512, 256, 0, stream>>>(bb, Cwb, y);
}